// Round 2
// baseline (273.298 us; speedup 1.0000x reference)
//
#include <hip/hip_runtime.h>
#include <math.h>

#define B 256
#define V 128000
#define S 8                    // segments per row -> grid = S x B = 2048 blocks
#define SEGV (V / S / 4)       // 4000 float4 per segment
#define BLOCK 256              // 4 waves
#define NOISE_MIN 1e-10f

// monotone (order-preserving) float32 -> uint32 encoding
__device__ __forceinline__ unsigned int enc_f32(float f) {
    unsigned int b = __float_as_uint(f);
    return (b & 0x80000000u) ? ~b : (b | 0x80000000u);
}

// pack so that u64 max == (max value, then min index)
__device__ __forceinline__ unsigned long long pack(float v, int i) {
    return ((unsigned long long)enc_f32(v) << 32) |
           (unsigned int)(0x7FFFFFFF - i);
}

__device__ __forceinline__ void upd(float v, int i, float& bv, int& bi) {
    if (v > bv || (v == bv && i < bi)) { bv = v; bi = i; }
}

__global__ __launch_bounds__(BLOCK) void sampler_kernel(
    const float* __restrict__ logits,
    const float* __restrict__ temps,
    const float* __restrict__ noise,
    unsigned long long* __restrict__ ws)
{
    const int seg = blockIdx.x;        // 0..S-1
    const int row = blockIdx.y;        // 0..B-1
    const float t = temps[row];
    const bool greedy = (t <= 0.0f);   // block-uniform
    const float invT = greedy ? 1.0f : (1.0f / t);

    const size_t base = (size_t)row * V;
    const float4* __restrict__ lg = reinterpret_cast<const float4*>(logits + base);
    const float4* __restrict__ nz = reinterpret_cast<const float4*>(noise + base);

    const int start = seg * SEGV;
    const int end   = start + SEGV;

    float bestVal = -INFINITY;
    int   bestIdx = 0x7FFFFFFF;

    if (greedy) {
        for (int v = start + threadIdx.x; v < end; v += BLOCK) {
            float4 l = lg[v];
            int i0 = v << 2;
            upd(l.x, i0 + 0, bestVal, bestIdx);
            upd(l.y, i0 + 1, bestVal, bestIdx);
            upd(l.z, i0 + 2, bestVal, bestIdx);
            upd(l.w, i0 + 3, bestVal, bestIdx);
        }
    } else {
        for (int v = start + threadIdx.x; v < end; v += BLOCK) {
            float4 l = lg[v];
            float4 n = nz[v];
            int i0 = v << 2;
            float kx = l.x * invT - __logf(fmaxf(n.x, NOISE_MIN));
            float ky = l.y * invT - __logf(fmaxf(n.y, NOISE_MIN));
            float kz = l.z * invT - __logf(fmaxf(n.z, NOISE_MIN));
            float kw = l.w * invT - __logf(fmaxf(n.w, NOISE_MIN));
            upd(kx, i0 + 0, bestVal, bestIdx);
            upd(ky, i0 + 1, bestVal, bestIdx);
            upd(kz, i0 + 2, bestVal, bestIdx);
            upd(kw, i0 + 3, bestVal, bestIdx);
        }
    }

    // wave (64-lane) butterfly max on the packed key — ordering matches
    // (max val, min idx) exactly
    unsigned long long best = pack(bestVal, bestIdx);
    #pragma unroll
    for (int off = 32; off > 0; off >>= 1) {
        unsigned long long o = __shfl_down(best, off, 64);
        if (o > best) best = o;
    }

    const int lane = threadIdx.x & 63;
    if (lane == 0) {
        atomicMax(&ws[row], best);   // device-scope by default on CDNA
    }
}

__global__ void decode_kernel(const unsigned long long* __restrict__ ws,
                              int* __restrict__ out)
{
    int i = threadIdx.x;
    out[i] = 0x7FFFFFFF - (int)(ws[i] & 0xFFFFFFFFu);
}

extern "C" void kernel_launch(void* const* d_in, const int* in_sizes, int n_in,
                              void* d_out, int out_size, void* d_ws, size_t ws_size,
                              hipStream_t stream) {
    const float* logits = (const float*)d_in[0];   // [B, V] f32
    const float* temps  = (const float*)d_in[1];   // [B]    f32
    const float* noise  = (const float*)d_in[2];   // [B, V] f32
    int* out = (int*)d_out;                        // [B] int32
    unsigned long long* ws = (unsigned long long*)d_ws;

    // ws is re-poisoned to 0xAA before every call; 0 is the identity for our
    // packed max (encoded floats are always > 0). Async memset is capturable.
    hipMemsetAsync(ws, 0, B * sizeof(unsigned long long), stream);

    dim3 grid(S, B);
    sampler_kernel<<<grid, BLOCK, 0, stream>>>(logits, temps, noise, ws);
    decode_kernel<<<1, B, 0, stream>>>(ws, out);
}